// Round 6
// baseline (3820.876 us; speedup 1.0000x reference)
//
#include <hip/hip_runtime.h>
#include <cstdint>
#include <cstddef>

// Problem constants
#define N_NEU   4096
#define N_IN    1024
#define B_SZ    8
#define T_STEPS 500
#define NBLK    512
#define FF_WORDS (B_SZ * T_STEPS * 16)

// ws layout:
//   [0)      u64 rec[2][8][128]   16 KB  (tagged half-mask records: {tag:32, mask:32})
//   [16384)  u64 typemask[64]     512 B  (per-chunk exc-type bit masks)
//   [16896)  u64 ffmask[B*T*16]   512 KB (input-spike bitmasks)
#define WS_REC_OFF   0
#define WS_TM_OFF    16384
#define WS_FFM_OFF   16896

// block k builds typemask[k]; lanes 0..31 zero this block's slice of rec
__global__ __launch_bounds__(64) void snn_init(const int* __restrict__ ci,
                                               unsigned long long* __restrict__ rec,
                                               unsigned long long* __restrict__ tmask) {
    const int k = blockIdx.x, l = threadIdx.x;
    unsigned long long m = __ballot(ci[(k << 6) + l] == 0);
    if (l == 0) tmask[k] = m;
    if (l < 32) rec[(k << 5) + l] = 0ULL;   // 64 blocks * 32 = 2048 words, tag=0
}

// input spikes (B,T,NI) -> bitmask words, 64 elems per word, ascending order
__global__ __launch_bounds__(256) void snn_ffmask(const float* __restrict__ inspk,
                                                  unsigned long long* __restrict__ ffmask) {
    int gid = blockIdx.x * 256 + threadIdx.x;
    int wid = gid >> 6, lane = gid & 63;
    int nw  = (gridDim.x * 256) >> 6;
    for (int w = wid; w < FF_WORDS; w += nw) {
        float v = inspk[(size_t)w * 64 + lane];
        unsigned long long m = __ballot(v > 0.5f);
        if (lane == 0) ffmask[w] = m;
    }
}

// extract set-bit indices (bit b of lane l's word -> index l*64+b) into lds,
// globally ascending. Returns total count. Operates within one wave.
__device__ __forceinline__ int extract_bits(unsigned long long m, int* lds, int lane) {
    int pc  = __popcll(m);
    int sum = pc;
#pragma unroll
    for (int d = 1; d < 64; d <<= 1) {
        int o = __shfl_up(sum, d, 64);
        if (lane >= d) sum += o;
    }
    int off   = sum - pc;           // exclusive prefix
    int total = __shfl(sum, 63, 64);
    int base  = lane << 6;
    while (m) {
        int bit = __builtin_ctzll(m);
        lds[off++] = base + bit;
        m &= m - 1ULL;
    }
    return total;
}

// sum of round(w*s) over listed rows, ascending order (bit-exact vs reference),
// 64-wide load pipelining.
__device__ __forceinline__ float gather_rows(const int* __restrict__ lst, int n,
                                             const float* __restrict__ base, float s) {
#pragma clang fp contract(off)
    float acc = 0.0f;
    int k = 0;
    for (; k + 64 <= n; k += 64) {
        float w[64];
#pragma unroll
        for (int u = 0; u < 64; ++u) w[u] = base[(size_t)lst[k + u] << 12];
#pragma unroll
        for (int u = 0; u < 64; ++u) acc += w[u] * s;
    }
    for (; k + 16 <= n; k += 16) {
        float w[16];
#pragma unroll
        for (int u = 0; u < 16; ++u) w[u] = base[(size_t)lst[k + u] << 12];
#pragma unroll
        for (int u = 0; u < 16; ++u) acc += w[u] * s;
    }
    for (; k < n; ++k) acc += base[(size_t)lst[k] << 12] * s;
    return acc;
}

__global__ __launch_bounds__(128) void snn_run(
    const float* __restrict__ W,       // (N,N) row j = presyn
    const float* __restrict__ Wff,     // (NI,N)
    const float* __restrict__ sf,      // (2,2)
    const float* __restrict__ sfff,    // (1,2)
    const int*   __restrict__ ci,      // (N)
    float*       __restrict__ out,     // (B,T,N)
    const unsigned long long* __restrict__ ffmask,
    const unsigned long long* __restrict__ tmask_g,
    unsigned long long* __restrict__ rec)
{
#pragma clang fp contract(off)
    const int tid  = threadIdx.x;
    const int lane = tid & 63;
    const int wv   = tid >> 6;
    // chunk pinned per XCD (bid%8); batch swizzled with bit8 so the two
    // co-resident blocks per CU serve different batches (stall overlap).
    const int bid   = blockIdx.x;
    const int chunk = ((bid & 7) << 3) | ((bid >> 6) & 7);
    const int b     = ((bid >> 3) & 7) ^ ((bid >> 8) & 1);
    const int i     = (chunk << 6) + lane;
    const int c     = ci[i];

    const float s_exc = sf[c];
    const float s_inh = sf[2 + c];
    const float s_ff  = sfff[c];

    // consumer role: lane l handles chunk l's record pair; its exc-type mask:
    const unsigned long long my_tm = tmask_g[lane];

    __shared__ int   lds_e[N_NEU];
    __shared__ int   lds_i[N_NEU];
    __shared__ int   lds_f[N_IN];
    __shared__ float smem_inh[64];

    // state lives in wave1's registers for all 500 steps
    float v = -70.0f, rf = 0.0f;
    float h0 = 0.0f, h1 = 0.0f, h2 = 0.0f, h3 = 0.0f;
    float g0 = 0.0f, g1 = 0.0f, g2 = 0.0f, g3 = 0.0f;

    const float aR0 = expf(-0.1f / 0.5f);
    const float aR1 = expf(-0.1f / 2.0f);
    const float aD0 = expf(-0.1f / 2.0f);
    const float aD1 = expf(-0.1f / 100.0f);
    const float aD2 = expf(-0.1f / 5.0f);
    const float kmem   = c ? (0.1f / 10.0f) : (0.1f / 20.0f);
    const float rsteps = c ? 10.0f : 20.0f;

    for (int t = 0; t < T_STEPS; ++t) {
        // ---- sync + mask delivery in ONE hop: poll tagged records; when the
        // tag check passes the masks are already in registers. Each u64 record
        // {tag,half-mask} is atomic -> no tearing, no producer waitcnt, no
        // separate mask load.
        unsigned long long mask = 0ULL;
        if (t > 0) {
            const unsigned long long* rp = rec + (((size_t)(t & 1) * 8) + b) * 128;
            unsigned long long r0, r1;
            for (;;) {
                r0 = __hip_atomic_load(rp + 2 * lane,     __ATOMIC_RELAXED,
                                       __HIP_MEMORY_SCOPE_AGENT);
                r1 = __hip_atomic_load(rp + 2 * lane + 1, __ATOMIC_RELAXED,
                                       __HIP_MEMORY_SCOPE_AGENT);
                bool ok = ((int)(r0 >> 32) >= t) && ((int)(r1 >> 32) >= t);
                if (__ballot(ok) == ~0ULL) break;
                __builtin_amdgcn_s_sleep(1);
            }
            mask = (r0 & 0xffffffffULL) | ((r1 & 0xffffffffULL) << 32);
        }

        float exc = 0.0f, ffd = 0.0f;
        if (wv == 0) {
            // inh gather (longer list) on wave0
            const int n = extract_bits(mask & ~my_tm, lds_i, lane);
            smem_inh[lane] = gather_rows(lds_i, n, W + i, s_inh);
        } else {
            // issue ff mask load early, then exc gather, then ff gather
            const unsigned long long mf =
                (lane < 16) ? ffmask[((size_t)b * T_STEPS + t) * 16 + lane] : 0ULL;
            const int n = extract_bits(mask & my_tm, lds_e, lane);
            exc = gather_rows(lds_e, n, W + i, s_exc);
            const int nf = extract_bits(mf, lds_f, lane);
            ffd = gather_rows(lds_f, nf, Wff + i, s_ff);
        }
        __syncthreads();

        if (wv == 1) {
            const float inh = smem_inh[lane];

            // ---- neuron update (identical fp op sequence to R1–R5: bit-exact) ----
            const float d0 = exc;
            const float d1 = 0.5f * exc;
            const float d2 = inh;
            const float d3 = ffd;

            h0 = fmaf(h0, aR0, d0);
            h1 = fmaf(h1, aR1, d1);
            h2 = fmaf(h2, aR0, d2);
            h3 = fmaf(h3, aR0, d3);
            g0 = fmaf(g0, aD0, (1.0f - aD0) * h0);
            g1 = fmaf(g1, aD1, (1.0f - aD1) * h1);
            g2 = fmaf(g2, aD2, (1.0f - aD2) * h2);
            g3 = fmaf(g3, aD0, (1.0f - aD0) * h3);

            const float p0 = g0 * (0.0f - v);
            const float p1 = g1 * (0.0f - v);
            const float p2 = g2 * (-80.0f - v);
            const float p3 = g3 * (0.0f - v);
            const float Isyn = ((p0 + p1) + p2) + p3;

            float vn = fmaf(kmem, (-70.0f - v) + Isyn / 10.0f, v);
            const bool refr = rf > 0.0f;
            if (refr) vn = -65.0f;
            const float sn = (!refr && (vn > -50.0f)) ? 1.0f : 0.0f;
            const bool spk = sn > 0.5f;
            v  = spk ? -65.0f : vn;
            rf = spk ? rsteps : fmaxf(rf - 1.0f, 0.0f);

            // publish step t+1's combined spike mask as two tagged records
            // (fire-and-forget; consumers split exc/inh via typemask)
            const unsigned long long sm = __ballot(spk);
            if (lane == 0) {
                const size_t base = (((size_t)((t + 1) & 1) * 8) + b) * 128 + 2 * chunk;
                const unsigned long long tag = ((unsigned long long)(t + 1)) << 32;
                __hip_atomic_store(&rec[base],     tag | (sm & 0xffffffffULL),
                                   __ATOMIC_RELAXED, __HIP_MEMORY_SCOPE_AGENT);
                __hip_atomic_store(&rec[base + 1], tag | (sm >> 32),
                                   __ATOMIC_RELAXED, __HIP_MEMORY_SCOPE_AGENT);
            }
            out[((size_t)b * T_STEPS + t) * N_NEU + i] = sn;
        }
        // wave0's next poll cannot pass until this block's wave1 publishes
        // (own record included), covering all LDS/smem cross-step hazards.
    }
}

extern "C" void kernel_launch(void* const* d_in, const int* in_sizes, int n_in,
                              void* d_out, int out_size, void* d_ws, size_t ws_size,
                              hipStream_t stream) {
    const float* inspk = (const float*)d_in[0];
    const float* W     = (const float*)d_in[1];
    const float* Wff   = (const float*)d_in[2];
    const float* sf    = (const float*)d_in[3];
    const float* sfff  = (const float*)d_in[4];
    const int*   ci    = (const int*)d_in[5];

    float* out = (float*)d_out;
    unsigned long long* rec    = (unsigned long long*)((char*)d_ws + WS_REC_OFF);
    unsigned long long* tmask  = (unsigned long long*)((char*)d_ws + WS_TM_OFF);
    unsigned long long* ffmask = (unsigned long long*)((char*)d_ws + WS_FFM_OFF);

    snn_init<<<64, 64, 0, stream>>>(ci, rec, tmask);
    snn_ffmask<<<1000, 256, 0, stream>>>(inspk, ffmask);
    snn_run<<<NBLK, 128, 0, stream>>>(W, Wff, sf, sfff, ci, out,
                                      ffmask, tmask, rec);
}

// Round 7
// 1726.017 us; speedup vs baseline: 2.2137x; 2.2137x over previous
//
#include <hip/hip_runtime.h>
#include <cstdint>
#include <cstddef>

// Problem constants
#define N_NEU   4096
#define N_IN    1024
#define B_SZ    8
#define T_STEPS 500
#define NSLICE  16
#define NBLK    (B_SZ * NSLICE)     // 128 blocks, 256 threads, 1 post/thread
#define FF_WORDS (B_SZ * T_STEPS * 16)

// ws layout:
//   [0)       int seq[8][64]        2 KB   (per-batch 64B seq line, 256B stride)
//   [2048)    u64 tmask[64]         512 B  (per-chunk exc-type bit masks)
//   [2560)    u64 mb[2][8][64]      8 KB   (dbuf spike masks, 64 words/batch)
//   [10752)   u64 ffmask[B*T*16]    512 KB (input-spike bitmasks)
//   [522752)  float ffdrive[T][B][N] 65.5 MB (precomputed FF drive)
#define WS_SEQ_OFF   0
#define WS_TM_OFF    2048
#define WS_MB_OFF    2560
#define WS_FFM_OFF   10752
#define WS_FFD_OFF   522752
#define WS_NEED_FFD  (522752 + (size_t)T_STEPS * B_SZ * N_NEU * 4)

__global__ __launch_bounds__(64) void snn_init(const int* __restrict__ ci,
                                               int* __restrict__ seq,
                                               unsigned long long* __restrict__ tmask,
                                               unsigned long long* __restrict__ mb) {
    const int k = blockIdx.x, l = threadIdx.x;   // 64 blocks x 64 threads
    unsigned long long m = __ballot(ci[(k << 6) + l] == 0);
    if (l == 0) tmask[k] = m;
    const int idx = (k << 6) + l;
    if (idx < 512)  seq[idx] = 0;
    if (idx < 1024) mb[idx] = 0ULL;
}

// input spikes (B,T,NI) -> bitmask words, 64 elems per word, ascending order
__global__ __launch_bounds__(256) void snn_ffmask(const float* __restrict__ inspk,
                                                  unsigned long long* __restrict__ ffmask) {
    int gid = blockIdx.x * 256 + threadIdx.x;
    int wid = gid >> 6, lane = gid & 63;
    int nw  = (gridDim.x * 256) >> 6;
    for (int w = wid; w < FF_WORDS; w += nw) {
        float v = inspk[(size_t)w * 64 + lane];
        unsigned long long m = __ballot(v > 0.5f);
        if (lane == 0) ffmask[w] = m;
    }
}

// Extract set-bit indices of a distributed 64x64-bit mask (lane l holds word l,
// bit b -> index l*64+b) into lds as typed entries (idx<<2)|ty, globally
// ascending; ty from tm_exc (bit set -> ty0/exc, clear -> ty1/inh). Pads to a
// multiple of 64 with sentinel entries (idx 0, ty 2). Returns real count.
__device__ __forceinline__ int extract_pad(unsigned long long m,
                                           unsigned long long tm_exc,
                                           int* lds, int lane) {
    int pc  = __popcll(m);
    int sum = pc;
#pragma unroll
    for (int d = 1; d < 64; d <<= 1) {
        int o = __shfl_up(sum, d, 64);
        if (lane >= d) sum += o;
    }
    int off   = sum - pc;           // exclusive prefix
    int total = __shfl(sum, 63, 64);
    int base  = lane << 6;
    while (m) {
        int bit = __builtin_ctzll(m);
        int ty  = ((tm_exc >> bit) & 1ULL) ? 0 : 1;
        lds[off++] = ((base + bit) << 2) | ty;
        m &= m - 1ULL;
    }
    int padcnt = (-total) & 63;
    if (lane < padcnt) lds[total + lane] = 2;   // sentinel: idx 0, ty 2
    return total;
}

// Combined typed gather: one 64-deep pipelined loop over a padded entry list;
// exc/inh accumulate into SEPARATE accumulators (each internally ascending ->
// bit-exact vs reference's two matmuls). Sentinels (ty2) contribute nowhere.
__device__ __forceinline__ void gather2(const int* __restrict__ lst, int npad,
                                        const float* __restrict__ base,
                                        float se, float si,
                                        float* oe, float* oi) {
#pragma clang fp contract(off)
    float ae = 0.0f, ai = 0.0f;
    for (int k = 0; k < npad; k += 64) {
        int   e[64];
        float w[64];
#pragma unroll
        for (int u = 0; u < 64; ++u) e[u] = lst[k + u];
#pragma unroll
        for (int u = 0; u < 64; ++u) w[u] = base[(size_t)(e[u] >> 2) << 12];
#pragma unroll
        for (int u = 0; u < 64; ++u) {
            const int ty = e[u] & 3;
            const float sc = (ty == 0) ? se : ((ty == 1) ? si : 0.0f);
            const float p  = w[u] * sc;           // per-element product rounding = W_eff
            ae = (ty == 0) ? ae + p : ae;
            ai = (ty == 1) ? ai + p : ai;
        }
    }
    *oe = ae; *oi = ai;
}

// Precompute FF drive for all (t,b) from ffmask (128 B/pair, not 4 KB inspk).
__global__ __launch_bounds__(64) void snn_ffpre(const unsigned long long* __restrict__ ffmask,
                                                const float* __restrict__ Wff,
                                                const float* __restrict__ sfff,
                                                const int*   __restrict__ ci,
                                                float*       __restrict__ ffdrive) {
#pragma clang fp contract(off)
    const int lane  = threadIdx.x;
    const int chunk = blockIdx.x & 63;
    const int tile  = blockIdx.x >> 6;     // 160 tiles of 25 (t,b) pairs
    const int i     = (chunk << 6) + lane;
    const float s_ff = sfff[ci[i]];
    __shared__ int lds_f[N_IN + 64];
    for (int p = tile * 25; p < tile * 25 + 25; ++p) {
        const int t = p >> 3, b = p & 7;
        const unsigned long long mf =
            (lane < 16) ? ffmask[((size_t)b * T_STEPS + t) * 16 + lane] : 0ULL;
        const int n = extract_pad(mf, ~0ULL, lds_f, lane);   // all ty0
        float fd, dummy;
        gather2(lds_f, (n + 63) & ~63, Wff + i, s_ff, 0.0f, &fd, &dummy);
        ffdrive[((size_t)t * B_SZ + b) * N_NEU + i] = fd;
    }
}

__global__ __launch_bounds__(256) void snn_run(
    const float* __restrict__ W,       // (N,N) row j = presyn
    const float* __restrict__ Wff,     // (NI,N)
    const float* __restrict__ sf,      // (2,2)
    const float* __restrict__ sfff,    // (1,2)
    const int*   __restrict__ ci,      // (N)
    float*       __restrict__ out,     // (B,T,N)
    const unsigned long long* __restrict__ ffmask,
    const unsigned long long* __restrict__ tmask_g,
    const float* __restrict__ ffdrive,
    int use_ffpre,
    int*         __restrict__ seq,
    unsigned long long* __restrict__ mb)
{
#pragma clang fp contract(off)
    const int tid   = threadIdx.x;
    const int lane  = tid & 63;
    const int wv    = tid >> 6;
    const int bid   = blockIdx.x;
    // slice from bits {0,1,2,6} (slice%8 pins W col-slice groups per XCD),
    // batch from bits {3,4,5}
    const int slice = (((bid >> 6) & 1) << 3) | (bid & 7);
    const int b     = (bid >> 3) & 7;
    const int i     = (slice << 8) + (wv << 6) + lane;    // my post neuron
    const int c     = ci[i];

    const float s_exc = sf[c];
    const float s_inh = sf[2 + c];
    const float s_ff  = sfff[c];

    const unsigned long long my_tm = tmask_g[lane];   // wave0's extract role

    __shared__ int lds_c[N_NEU + 64];
    __shared__ int lds_f[N_IN + 64];
    __shared__ int s_ne, s_nf;

    int* seqb = seq + b * 64;                             // one 64B line
    unsigned long long* mb_b[2] = { mb + (size_t)b * 64, mb + 512 + (size_t)b * 64 };

    // state lives in registers for all 500 steps (1 post/thread)
    float v = -70.0f, rf = 0.0f;
    float h0 = 0.0f, h1 = 0.0f, h2 = 0.0f, h3 = 0.0f;
    float g0 = 0.0f, g1 = 0.0f, g2 = 0.0f, g3 = 0.0f;

    const float aR0 = expf(-0.1f / 0.5f);
    const float aR1 = expf(-0.1f / 2.0f);
    const float aD0 = expf(-0.1f / 2.0f);
    const float aD1 = expf(-0.1f / 100.0f);
    const float aD2 = expf(-0.1f / 5.0f);
    const float kmem   = c ? (0.1f / 10.0f) : (0.1f / 20.0f);
    const float rsteps = c ? 10.0f : 20.0f;

    for (int t = 0; t < T_STEPS; ++t) {
        if (wv == 0) {
            if (t > 0) {
                // single-line poll, wave0 only (128 poller waves device-wide)
                for (;;) {
                    int sv = (lane < NSLICE)
                        ? __hip_atomic_load(&seqb[lane], __ATOMIC_RELAXED,
                                            __HIP_MEMORY_SCOPE_AGENT)
                        : t;
                    if (__ballot(sv >= t) == ~0ULL) break;
                    __builtin_amdgcn_s_sleep(1);
                }
                asm volatile("" ::: "memory");   // keep mask loads below the poll
            }
            unsigned long long mw = 0ULL;
            if (t > 0)
                mw = __hip_atomic_load(&mb_b[t & 1][lane], __ATOMIC_RELAXED,
                                       __HIP_MEMORY_SCOPE_AGENT);
            const int n = extract_pad(mw, my_tm, lds_c, lane);
            if (lane == 0) s_ne = n;
            if (!use_ffpre) {
                const unsigned long long mf =
                    (lane < 16) ? ffmask[((size_t)b * T_STEPS + t) * 16 + lane] : 0ULL;
                const int nf = extract_pad(mf, ~0ULL, lds_f, lane);
                if (lane == 0) s_nf = nf;
            }
        }
        __syncthreads();   // A: lists + counts published to all 4 waves

        float ffd = 0.0f;
        if (use_ffpre)
            ffd = ffdrive[((size_t)t * B_SZ + b) * N_NEU + i];  // issued early

        float exc, inh;
        gather2(lds_c, (s_ne + 63) & ~63, W + i, s_exc, s_inh, &exc, &inh);
        if (!use_ffpre) {
            float fd, dummy;
            gather2(lds_f, (s_nf + 63) & ~63, Wff + i, s_ff, 0.0f, &fd, &dummy);
            ffd = fd;
        }

        // ---- neuron update (identical fp op sequence to R1–R6: bit-exact) ----
        const float d0 = exc;
        const float d1 = 0.5f * exc;
        const float d2 = inh;
        const float d3 = ffd;

        h0 = fmaf(h0, aR0, d0);
        h1 = fmaf(h1, aR1, d1);
        h2 = fmaf(h2, aR0, d2);
        h3 = fmaf(h3, aR0, d3);
        g0 = fmaf(g0, aD0, (1.0f - aD0) * h0);
        g1 = fmaf(g1, aD1, (1.0f - aD1) * h1);
        g2 = fmaf(g2, aD2, (1.0f - aD2) * h2);
        g3 = fmaf(g3, aD0, (1.0f - aD0) * h3);

        const float p0 = g0 * (0.0f - v);
        const float p1 = g1 * (0.0f - v);
        const float p2 = g2 * (-80.0f - v);
        const float p3 = g3 * (0.0f - v);
        const float Isyn = ((p0 + p1) + p2) + p3;

        float vn = fmaf(kmem, (-70.0f - v) + Isyn / 10.0f, v);
        const bool refr = rf > 0.0f;
        if (refr) vn = -65.0f;
        const float sn = (!refr && (vn > -50.0f)) ? 1.0f : 0.0f;
        const bool spk = sn > 0.5f;
        v  = spk ? -65.0f : vn;
        rf = spk ? rsteps : fmaxf(rf - 1.0f, 0.0f);

        // publish this wave's 64-post spike word for step t+1 + output
        const unsigned long long sm = __ballot(spk);
        if (lane == 0)
            __hip_atomic_store(&mb_b[(t + 1) & 1][(slice << 2) | wv], sm,
                               __ATOMIC_RELAXED, __HIP_MEMORY_SCOPE_AGENT);
        out[((size_t)b * T_STEPS + t) * N_NEU + i] = sn;

        __builtin_amdgcn_s_waitcnt(0);   // drain my mask word + out store
        __syncthreads();                 // B: all 4 words of this block drained
        if (wv == 0 && lane == 0)
            __hip_atomic_store(&seqb[slice], t + 1,
                               __ATOMIC_RELAXED, __HIP_MEMORY_SCOPE_AGENT);
        // wave0 proceeds to poll t+1; other waves park at A — lds_c rewrite is
        // safe, and wave0 can't pass its own poll until this block published.
    }
}

extern "C" void kernel_launch(void* const* d_in, const int* in_sizes, int n_in,
                              void* d_out, int out_size, void* d_ws, size_t ws_size,
                              hipStream_t stream) {
    const float* inspk = (const float*)d_in[0];
    const float* W     = (const float*)d_in[1];
    const float* Wff   = (const float*)d_in[2];
    const float* sf    = (const float*)d_in[3];
    const float* sfff  = (const float*)d_in[4];
    const int*   ci    = (const int*)d_in[5];

    float* out = (float*)d_out;
    int*                seq     = (int*)((char*)d_ws + WS_SEQ_OFF);
    unsigned long long* tmask   = (unsigned long long*)((char*)d_ws + WS_TM_OFF);
    unsigned long long* mb      = (unsigned long long*)((char*)d_ws + WS_MB_OFF);
    unsigned long long* ffmask  = (unsigned long long*)((char*)d_ws + WS_FFM_OFF);
    float*              ffdrive = (float*)((char*)d_ws + WS_FFD_OFF);
    const int use_ffpre = (ws_size >= WS_NEED_FFD) ? 1 : 0;

    snn_init<<<64, 64, 0, stream>>>(ci, seq, tmask, mb);
    snn_ffmask<<<1000, 256, 0, stream>>>(inspk, ffmask);
    if (use_ffpre)
        snn_ffpre<<<160 * 64, 64, 0, stream>>>(ffmask, Wff, sfff, ci, ffdrive);
    snn_run<<<NBLK, 256, 0, stream>>>(W, Wff, sf, sfff, ci, out,
                                      ffmask, tmask, ffdrive, use_ffpre, seq, mb);
}